// Round 10
// baseline (720.856 us; speedup 1.0000x reference)
//
#include <hip/hip_runtime.h>
#include <math.h>

// Problem constants
constexpr int CB = 2, CN = 1024, CD = 768, CH = 16, CHD = 48, CHID = 1536;
constexpr int CT = CB * CN;              // 2048 tokens
constexpr float CEPS = 1e-5f;

typedef __bf16 bf16_t;
typedef __bf16 bf16x8 __attribute__((ext_vector_type(8)));
typedef __bf16 bf16x4 __attribute__((ext_vector_type(4)));
typedef float  f32x4  __attribute__((ext_vector_type(4)));

__device__ __forceinline__ float sigf(float x) { return 1.f / (1.f + expf(-x)); }

// async global->LDS, 16B per lane, LDS dest = wave-uniform base + lane*16
__device__ __forceinline__ void gload16(const void* g, void* l) {
    __builtin_amdgcn_global_load_lds((const __attribute__((address_space(1))) void*)g,
                                     (__attribute__((address_space(3))) void*)l, 16, 0, 0);
}

// ---------------------------------------------------------------------------
// LN-pre: an = LN(a) (fp32), snbf = bf16(LN(s)*snw), optional sbf = bf16(s).
// One 256-thread block per token row.
// ---------------------------------------------------------------------------
__global__ __launch_bounds__(256) void ln_pre_k(
    const float* __restrict__ a, const float* __restrict__ s,
    const float* __restrict__ snw,
    float* __restrict__ an, bf16_t* __restrict__ snbf, bf16_t* __restrict__ sbf)
{
    __shared__ float r4[4][4];
    const int row = blockIdx.x;
    const int tid = threadIdx.x;
    const float* ar = a + (size_t)row * CD;
    const float* sr = s + (size_t)row * CD;

    float av[3], sv[3];
    float suma = 0.f, sqa = 0.f, sums = 0.f, sqs = 0.f;
#pragma unroll
    for (int j = 0; j < 3; ++j) {
        const int i = tid + j * 256;
        av[j] = ar[i]; sv[j] = sr[i];
        suma += av[j]; sqa += av[j] * av[j];
        sums += sv[j]; sqs += sv[j] * sv[j];
    }
#pragma unroll
    for (int o = 32; o > 0; o >>= 1) {
        suma += __shfl_down(suma, o, 64);
        sqa  += __shfl_down(sqa,  o, 64);
        sums += __shfl_down(sums, o, 64);
        sqs  += __shfl_down(sqs,  o, 64);
    }
    const int wv = tid >> 6;
    if ((tid & 63) == 0) { r4[0][wv] = suma; r4[1][wv] = sqa; r4[2][wv] = sums; r4[3][wv] = sqs; }
    __syncthreads();
    suma = r4[0][0] + r4[0][1] + r4[0][2] + r4[0][3];
    sqa  = r4[1][0] + r4[1][1] + r4[1][2] + r4[1][3];
    sums = r4[2][0] + r4[2][1] + r4[2][2] + r4[2][3];
    sqs  = r4[3][0] + r4[3][1] + r4[3][2] + r4[3][3];

    const float inv_d = 1.f / (float)CD;
    const float ma = suma * inv_d;
    const float ra = rsqrtf(sqa * inv_d - ma * ma + CEPS);
    const float ms = sums * inv_d;
    const float rs = rsqrtf(sqs * inv_d - ms * ms + CEPS);

#pragma unroll
    for (int j = 0; j < 3; ++j) {
        const int i = tid + j * 256;
        an[(size_t)row * CD + i]   = (av[j] - ma) * ra;
        snbf[(size_t)row * CD + i] = (bf16_t)((sv[j] - ms) * rs * snw[i]);
        if (sbf) sbf[(size_t)row * CD + i] = (bf16_t)sv[j];
    }
}

// ---------------------------------------------------------------------------
// Merged transpose-convert: all 15 weight packs in ONE dispatch.
// Each 32x32 tile: dst[row_ofs+n][k] = bf16(src[k][col_ofs+n]).
// ---------------------------------------------------------------------------
struct TJob { const float* src; bf16_t* dst; int ld_src, col_ofs, ld_dst, row_ofs, ntx, cnt; };
struct TJobs { TJob j[15]; };

__global__ __launch_bounds__(256) void tcvt_all_k(TJobs jobs)
{
    __shared__ float t[32][33];
    int tb = blockIdx.x;
    int ji = 0;
    while (ji < 14 && tb >= jobs.j[ji].cnt) { tb -= jobs.j[ji].cnt; ++ji; }
    const float* src = jobs.j[ji].src;
    bf16_t* dst      = jobs.j[ji].dst;
    const int ld_src = jobs.j[ji].ld_src, col_ofs = jobs.j[ji].col_ofs;
    const int ld_dst = jobs.j[ji].ld_dst, row_ofs = jobs.j[ji].row_ofs;
    const int ntx    = jobs.j[ji].ntx;
    const int n0 = (tb % ntx) * 32;
    const int k0 = (tb / ntx) * 32;
    const int tx = threadIdx.x & 31, ty = threadIdx.x >> 5;   // ty 0..7
#pragma unroll
    for (int i = 0; i < 4; ++i)
        t[ty + 8 * i][tx] = src[(size_t)(k0 + ty + 8 * i) * ld_src + col_ofs + n0 + tx];
    __syncthreads();
#pragma unroll
    for (int i = 0; i < 4; ++i)
        dst[(size_t)(row_ofs + n0 + ty + 8 * i) * ld_dst + k0 + tx] = (bf16_t)t[tx][ty + 8 * i];
}

// ---------------------------------------------------------------------------
// bf16 MFMA GEMM: C[M,N] = A[M,K] @ B[K,N], with B stored TRANSPOSED: Bt[N][K].
// 128x128 tile, BK=32, 256 threads = 4 waves (2x2), each wave 64x64 out
// (4x4 fragments of 16x16, mfma_f32_16x16x32_bf16). Double-buffered LDS
// staged via global_load_lds (m97 structure). fp32 accumulate; C fp32 or bf16.
// ---------------------------------------------------------------------------
template<bool CBF16>
__global__ __launch_bounds__(256) void mgemm_k(
    const bf16_t* __restrict__ A, const int lda,
    const bf16_t* __restrict__ Bt, const int K,
    void* __restrict__ Cv, const int ldc)
{
    __shared__ __align__(16) bf16_t lA[2][128 * 32];
    __shared__ __align__(16) bf16_t lB[2][128 * 32];
    const int tid  = threadIdx.x;
    const int lane = tid & 63;
    const int m0 = blockIdx.y * 128;
    const int n0 = blockIdx.x * 128;
    const int wv = tid >> 6;
    const int wr = (wv >> 1) * 64;
    const int wc = (wv & 1) * 64;

    f32x4 acc[4][4] = {};

    // staging geometry: chunk c (16B) -> row c>>2, k-group c&3 (8 bf16)
    const int r0 = tid >> 2,        kg0 = (tid & 3) * 8;          // issue 0 chunk=tid
    const int r1 = (tid + 256) >> 2, kg1 = kg0;                   // issue 1 chunk=tid+256
    const int wbase = (tid & ~63) * 16;                           // wave-uniform LDS byte base

#define STAGE(buf, kt)                                                                  \
    do {                                                                                \
        gload16(A  + (size_t)(m0 + r0) * lda + (kt) + kg0, (char*)lA[buf] + wbase);     \
        gload16(A  + (size_t)(m0 + r1) * lda + (kt) + kg1, (char*)lA[buf] + 4096 + wbase); \
        gload16(Bt + (size_t)(n0 + r0) * K   + (kt) + kg0, (char*)lB[buf] + wbase);     \
        gload16(Bt + (size_t)(n0 + r1) * K   + (kt) + kg1, (char*)lB[buf] + 4096 + wbase); \
    } while (0)

    const int nt = K >> 5;
    STAGE(0, 0);
    __syncthreads();

    const int afr = wr + (lane & 15);
    const int bfr_ = wc + (lane & 15);
    const int kof = (lane >> 4) * 8;

    for (int t = 0; t < nt; ++t) {
        const int buf = t & 1;
        if (t + 1 < nt) STAGE(buf ^ 1, (t + 1) << 5);
        bf16x8 af[4], bfv[4];
#pragma unroll
        for (int i = 0; i < 4; ++i) {
            af[i]  = *(const bf16x8*)&lA[buf][(afr + i * 16) * 32 + kof];
            bfv[i] = *(const bf16x8*)&lB[buf][(bfr_ + i * 16) * 32 + kof];
        }
#pragma unroll
        for (int mi = 0; mi < 4; ++mi)
#pragma unroll
            for (int ni = 0; ni < 4; ++ni)
                acc[mi][ni] = __builtin_amdgcn_mfma_f32_16x16x32_bf16(af[mi], bfv[ni], acc[mi][ni], 0, 0, 0);
        __syncthreads();
    }
#undef STAGE

    // C/D layout: col = lane&15, row = (lane>>4)*4 + reg   [verified m89/m91]
    const int crow = m0 + wr + ((lane >> 4) << 2);
    const int ccol = n0 + wc + (lane & 15);
#pragma unroll
    for (int mi = 0; mi < 4; ++mi)
#pragma unroll
        for (int r = 0; r < 4; ++r) {
            const size_t ro = (size_t)(crow + mi * 16 + r) * ldc + ccol;
#pragma unroll
            for (int ni = 0; ni < 4; ++ni) {
                if (CBF16) ((bf16_t*)Cv)[ro + ni * 16] = (bf16_t)acc[mi][ni][r];
                else       ((float*)Cv)[ro + ni * 16]  = acc[mi][ni][r];
            }
        }
}

// ---------------------------------------------------------------------------
// Elementwise combines (all fp32 math, 4 elements/thread, exact grids)
// ---------------------------------------------------------------------------
// b = an * sigmoid(ss + ssb) + sb ; ss|sb packed [T][1536] bf16
__global__ __launch_bounds__(256) void comb_adaln_k(
    const float* __restrict__ an, const bf16_t* __restrict__ ssb_mat,
    const float* __restrict__ bias, bf16_t* __restrict__ out)
{
    const int i4 = (blockIdx.x * 256 + threadIdx.x) * 4;
    const int row = i4 / CD, col = i4 - row * CD;
    const float4 anv = *(const float4*)&an[i4];
    const bf16x4 ssv = *(const bf16x4*)&ssb_mat[(size_t)row * 1536 + col];
    const bf16x4 sbv = *(const bf16x4*)&ssb_mat[(size_t)row * 1536 + 768 + col];
    const float4 bv  = *(const float4*)&bias[col];
    bf16x4 o;
    o[0] = (bf16_t)(anv.x * sigf((float)ssv[0] + bv.x) + (float)sbv[0]);
    o[1] = (bf16_t)(anv.y * sigf((float)ssv[1] + bv.y) + (float)sbv[1]);
    o[2] = (bf16_t)(anv.z * sigf((float)ssv[2] + bv.z) + (float)sbv[2]);
    o[3] = (bf16_t)(anv.w * sigf((float)ssv[3] + bv.w) + (float)sbv[3]);
    *(bf16x4*)&out[i4] = o;
}

// dst = base + sigmoid(gate_pre + bias) * x   (gates [T][1536] fp32, col offset g_ofs)
__global__ __launch_bounds__(256) void gateadd_k(
    const float* __restrict__ base, const float* __restrict__ gates, const int g_ofs,
    const float* __restrict__ bias, const float* __restrict__ x, float* __restrict__ dst)
{
    const int i4 = (blockIdx.x * 256 + threadIdx.x) * 4;
    const int row = i4 / CD, col = i4 - row * CD;
    const float4 bv = *(const float4*)&base[i4];
    const float4 gv = *(const float4*)&gates[(size_t)row * 1536 + g_ofs + col];
    const float4 bi = *(const float4*)&bias[col];
    const float4 xv = *(const float4*)&x[i4];
    float4 o;
    o.x = bv.x + sigf(gv.x + bi.x) * xv.x;
    o.y = bv.y + sigf(gv.y + bi.y) * xv.y;
    o.z = bv.z + sigf(gv.z + bi.z) * xv.z;
    o.w = bv.w + sigf(gv.w + bi.w) * xv.w;
    *(float4*)&dst[i4] = o;
}

// hidden = silu(gate) * u * h ; ugh packed [T][4608] bf16 (u|gate|h)
__global__ __launch_bounds__(256) void mlp_comb_k(
    const bf16_t* __restrict__ ugh, bf16_t* __restrict__ hidden)
{
    const int i4 = (blockIdx.x * 256 + threadIdx.x) * 4;
    const int row = i4 / CHID, col = i4 - row * CHID;
    const bf16x4 uv = *(const bf16x4*)&ugh[(size_t)row * 4608 + col];
    const bf16x4 gv = *(const bf16x4*)&ugh[(size_t)row * 4608 + 1536 + col];
    const bf16x4 hv = *(const bf16x4*)&ugh[(size_t)row * 4608 + 3072 + col];
    bf16x4 o;
#pragma unroll
    for (int j = 0; j < 4; ++j) {
        const float g = (float)gv[j];
        o[j] = (bf16_t)(g * sigf(g) * (float)uv[j] * (float)hv[j]);
    }
    *(bf16x4*)&hidden[i4] = o;
}

// ---------------------------------------------------------------------------
// Flash attention, fp32, QBLK=32 rows/block, 8 threads/row, 1 row/thread.
// Grid = 1024 blocks (4/CU) for occupancy; per-thread state stays ~96 VGPR
// (no spill — round-8 lesson). Keys interleaved key = kk*8 + oct: oct word
// offsets 52*oct mod 32 = {0,20,8,28,16,4,24,12} cover all 32 banks once;
// same-address reads across row-groups broadcast. Fuses q-bias on load and
// og = o * sigmoid(g) epilogue (bf16 out).
// ---------------------------------------------------------------------------
__global__ __launch_bounds__(256) void attn_k(
    const float* __restrict__ qkvg, const float* __restrict__ qb,
    const float* __restrict__ z, bf16_t* __restrict__ og)
{
    __shared__ float kls[64][52];
    __shared__ float vls[64][52];
    const int tid  = threadIdx.x;
    const int qb_i = blockIdx.x;     // 0..31
    const int h    = blockIdx.y;
    const int b    = blockIdx.z;
    const int r    = tid >> 3;       // 0..31 row within block
    const int oct  = tid & 7;
    const int qrow = qb_i * 32 + r;
    const float scale = 0.14433756729740643f; // 1/sqrt(48)

    float qreg[48];
    const float* qp = qkvg + (size_t)(b * CN + qrow) * 3072 + h * CHD;
#pragma unroll
    for (int j = 0; j < 12; ++j) {
        const float4 t4 = *(const float4*)(qp + j * 4);
        const float4 b4 = *(const float4*)(qb + h * CHD + j * 4);
        qreg[j * 4 + 0] = t4.x + b4.x; qreg[j * 4 + 1] = t4.y + b4.y;
        qreg[j * 4 + 2] = t4.z + b4.z; qreg[j * 4 + 3] = t4.w + b4.w;
    }
    float acc[48];
#pragma unroll
    for (int d = 0; d < 48; ++d) acc[d] = 0.f;
    float m = -1e30f, l = 0.f;

    const float* zbase = z + (((size_t)(h * CB + b)) * CN + qrow) * CN;
    const float* kbase = qkvg + 768  + h * CHD;
    const float* vbase = qkvg + 1536 + h * CHD;

    for (int kt = 0; kt < CN; kt += 64) {
        __syncthreads();
#pragma unroll
        for (int j = 0; j < 3; ++j) {
            const int idx = tid + j * 256;       // 0..767
            const int key = idx / 12;
            const int d4  = idx - key * 12;
            const size_t gofs = (size_t)(b * CN + kt + key) * 3072 + d4 * 4;
            *(float4*)&kls[key][d4 * 4] = *(const float4*)(kbase + gofs);
            *(float4*)&vls[key][d4 * 4] = *(const float4*)(vbase + gofs);
        }
        __syncthreads();

        float sc[8];
#pragma unroll
        for (int kk = 0; kk < 8; ++kk) {
            const int key = kk * 8 + oct;
            float dt = 0.f;
#pragma unroll
            for (int j = 0; j < 12; ++j) {
                const float4 k4 = *(const float4*)&kls[key][j * 4];
                dt = fmaf(qreg[j * 4 + 0], k4.x, dt);
                dt = fmaf(qreg[j * 4 + 1], k4.y, dt);
                dt = fmaf(qreg[j * 4 + 2], k4.z, dt);
                dt = fmaf(qreg[j * 4 + 3], k4.w, dt);
            }
            sc[kk] = dt * scale + zbase[kt + kk * 8 + oct];
        }
        float tmax = sc[0];
#pragma unroll
        for (int kk = 1; kk < 8; ++kk) tmax = fmaxf(tmax, sc[kk]);
        tmax = fmaxf(tmax, __shfl_xor(tmax, 1, 8));
        tmax = fmaxf(tmax, __shfl_xor(tmax, 2, 8));
        tmax = fmaxf(tmax, __shfl_xor(tmax, 4, 8));
        const float mnew = fmaxf(m, tmax);
        const float resc = expf(m - mnew);
        m = mnew;
        l *= resc;
#pragma unroll
        for (int d = 0; d < 48; ++d) acc[d] *= resc;

        float p[8]; float ps = 0.f;
#pragma unroll
        for (int kk = 0; kk < 8; ++kk) { p[kk] = expf(sc[kk] - mnew); ps += p[kk]; }
        l += ps;

#pragma unroll
        for (int kk = 0; kk < 8; ++kk) {
            const int key = kk * 8 + oct;
            const float pv = p[kk];
#pragma unroll
            for (int j = 0; j < 12; ++j) {
                const float4 v4 = *(const float4*)&vls[key][j * 4];
                acc[j * 4 + 0] = fmaf(pv, v4.x, acc[j * 4 + 0]);
                acc[j * 4 + 1] = fmaf(pv, v4.y, acc[j * 4 + 1]);
                acc[j * 4 + 2] = fmaf(pv, v4.z, acc[j * 4 + 2]);
                acc[j * 4 + 3] = fmaf(pv, v4.w, acc[j * 4 + 3]);
            }
        }
    }

    // reduce partials across the 8-thread oct group
    l += __shfl_xor(l, 1, 8);
    l += __shfl_xor(l, 2, 8);
    l += __shfl_xor(l, 4, 8);
    const float inv = 1.f / l;
#pragma unroll
    for (int d = 0; d < 48; ++d) {
        acc[d] += __shfl_xor(acc[d], 1, 8);
        acc[d] += __shfl_xor(acc[d], 2, 8);
        acc[d] += __shfl_xor(acc[d], 4, 8);
    }
    if (oct == 0) {
        const float* gp = qkvg + (size_t)(b * CN + qrow) * 3072 + 2304 + h * CHD;
        bf16_t* op = og + (size_t)(b * CN + qrow) * CD + h * CHD;
#pragma unroll
        for (int j = 0; j < 12; ++j) {
            const float4 gv = *(const float4*)(gp + j * 4);
            bf16x4 o;
            o[0] = (bf16_t)(acc[j * 4 + 0] * inv * sigf(gv.x));
            o[1] = (bf16_t)(acc[j * 4 + 1] * inv * sigf(gv.y));
            o[2] = (bf16_t)(acc[j * 4 + 2] * inv * sigf(gv.z));
            o[3] = (bf16_t)(acc[j * 4 + 3] * inv * sigf(gv.w));
            *(bf16x4*)(op + j * 4) = o;
        }
    }
}

// ---------------------------------------------------------------------------
// launch
// ---------------------------------------------------------------------------
extern "C" void kernel_launch(void* const* d_in, const int* in_sizes, int n_in,
                              void* d_out, int out_size, void* d_ws, size_t ws_size,
                              hipStream_t stream)
{
    const float* a       = (const float*)d_in[0];
    const float* s       = (const float*)d_in[1];
    const float* z       = (const float*)d_in[2];
    const float* a1_snw  = (const float*)d_in[3];
    const float* a1_ssw  = (const float*)d_in[4];
    const float* a1_ssb  = (const float*)d_in[5];
    const float* a1_sbw  = (const float*)d_in[6];
    const float* q_w     = (const float*)d_in[7];
    const float* q_b     = (const float*)d_in[8];
    const float* k_w     = (const float*)d_in[9];
    const float* v_w     = (const float*)d_in[10];
    const float* g_w     = (const float*)d_in[11];
    const float* o_w     = (const float*)d_in[12];
    const float* outproj_w = (const float*)d_in[13];
    const float* outproj_b = (const float*)d_in[14];
    const float* a2_snw  = (const float*)d_in[15];
    const float* a2_ssw  = (const float*)d_in[16];
    const float* a2_ssb  = (const float*)d_in[17];
    const float* a2_sbw  = (const float*)d_in[18];
    const float* swish_w = (const float*)d_in[19];
    const float* a2b_w   = (const float*)d_in[20];
    const float* b2a_w   = (const float*)d_in[21];
    const float* op_w    = (const float*)d_in[22];
    const float* op_b    = (const float*)d_in[23];
    float* out = (float*)d_out;
    char*  wsb = (char*)d_ws;

    // ---- workspace slabs (aligned 256B); ~95 MB total ----
    size_t off = 0;
    auto alloc = [&](size_t bytes) { char* p = wsb + off; off = (off + bytes + 255) & ~(size_t)255; return p; };
    float*  A_an    = (float*) alloc((size_t)CT * CD * 4);     // an / an2 / y2
    bf16_t* B_sn    = (bf16_t*)alloc((size_t)CT * CD * 2);     // sn / sn2
    bf16_t* C_sbf   = (bf16_t*)alloc((size_t)CT * CD * 2);     // bf16(s)
    bf16_t* D_ssb   = (bf16_t*)alloc((size_t)CT * 1536 * 2);   // ss|sb (x2) / hidden
    bf16_t* E_act   = (bf16_t*)alloc((size_t)CT * CD * 2);     // b_bf / og_bf / a2_bf
    char*   F_big   = (char*)  alloc((size_t)CT * 3072 * 4);   // qkvg f32 / ugh bf16
    float*  G_gates = (float*) alloc((size_t)CT * 1536 * 4);   // gate pre-acts (live to end)
    float*  H_anew  = (float*) alloc((size_t)CT * CD * 4);
    float*  J_x     = (float*) alloc((size_t)CT * CD * 4);
    bf16_t* W1t     = (bf16_t*)alloc((size_t)1536 * 768 * 2);  // [ssw|sbw]^T
    bf16_t* W2t     = (bf16_t*)alloc((size_t)1536 * 768 * 2);
    bf16_t* Wqkvgt  = (bf16_t*)alloc((size_t)3072 * 768 * 2);
    bf16_t* Wgt     = (bf16_t*)alloc((size_t)1536 * 768 * 2);  // [outproj|op]^T
    bf16_t* W3t     = (bf16_t*)alloc((size_t)4608 * 768 * 2);  // [u|gate|a2b]^T
    bf16_t* Wot     = (bf16_t*)alloc((size_t)768 * 768 * 2);
    bf16_t* Wb2at   = (bf16_t*)alloc((size_t)768 * 1536 * 2);
    float*  qkvg_f  = (float*)F_big;
    bf16_t* ugh_b   = (bf16_t*)F_big;
    bf16_t* hidden  = D_ssb;
    float*  y2      = A_an;

    const dim3 blk(256);

    // ---- 1. pack weights -> transposed bf16 (single dispatch, 10944 tiles) ----
    TJobs tj = {{
        {a1_ssw,    W1t,    768,  0,    768,  0,    24, 576},
        {a1_sbw,    W1t,    768,  0,    768,  768,  24, 576},
        {q_w,       Wqkvgt, 768,  0,    768,  0,    24, 576},
        {k_w,       Wqkvgt, 768,  0,    768,  768,  24, 576},
        {v_w,       Wqkvgt, 768,  0,    768,  1536, 24, 576},
        {g_w,       Wqkvgt, 768,  0,    768,  2304, 24, 576},
        {outproj_w, Wgt,    768,  0,    768,  0,    24, 576},
        {op_w,      Wgt,    768,  0,    768,  768,  24, 576},
        {a2_ssw,    W2t,    768,  0,    768,  0,    24, 576},
        {a2_sbw,    W2t,    768,  0,    768,  768,  24, 576},
        {swish_w,   W3t,    3072, 0,    768,  0,    48, 1152},
        {swish_w,   W3t,    3072, 1536, 768,  1536, 48, 1152},
        {a2b_w,     W3t,    1536, 0,    768,  3072, 48, 1152},
        {o_w,       Wot,    768,  0,    768,  0,    24, 576},
        {b2a_w,     Wb2at,  768,  0,    1536, 0,    24, 1152},
    }};
    tcvt_all_k<<<dim3(10944), blk, 0, stream>>>(tj);

    const dim3 e768(CT * CD / 4 / 256);       // 1536 blocks
    const dim3 e1536(CT * CHID / 4 / 256);    // 3072 blocks
#define GRID(N) dim3((N) / 128, CT / 128)

    // ---- 2. adaln1 ----
    ln_pre_k<<<CT, blk, 0, stream>>>(a, s, a1_snw, A_an, B_sn, C_sbf);
    mgemm_k<true ><<<GRID(1536), blk, 0, stream>>>(B_sn, CD, W1t, 768, D_ssb, 1536);
    comb_adaln_k<<<e768, blk, 0, stream>>>(A_an, D_ssb, a1_ssb, E_act);
    // ---- 3. qkvg + gates ----
    mgemm_k<false><<<GRID(3072), blk, 0, stream>>>(E_act, CD, Wqkvgt, 768, qkvg_f, 3072);
    mgemm_k<false><<<GRID(1536), blk, 0, stream>>>(C_sbf, CD, Wgt, 768, G_gates, 1536);
    // ---- 4. attention (writes og = o*sigmoid(g), bf16) ----
    attn_k<<<dim3(CN / 32, CH, CB), blk, 0, stream>>>(qkvg_f, q_b, z, E_act);
    // ---- 5. x = og @ o_w ; anew = a + sigmoid(outproj)*x ----
    mgemm_k<false><<<GRID(768), blk, 0, stream>>>(E_act, CD, Wot, 768, J_x, 768);
    gateadd_k<<<e768, blk, 0, stream>>>(a, G_gates, 0, outproj_b, J_x, H_anew);
    // ---- 6. adaln2 ----
    ln_pre_k<<<CT, blk, 0, stream>>>(H_anew, s, a2_snw, A_an, B_sn, nullptr);
    mgemm_k<true ><<<GRID(1536), blk, 0, stream>>>(B_sn, CD, W2t, 768, D_ssb, 1536);
    comb_adaln_k<<<e768, blk, 0, stream>>>(A_an, D_ssb, a2_ssb, E_act);
    // ---- 7. MLP ----
    mgemm_k<true ><<<GRID(4608), blk, 0, stream>>>(E_act, CD, W3t, 768, ugh_b, 4608);
    mlp_comb_k<<<e1536, blk, 0, stream>>>(ugh_b, hidden);
    mgemm_k<false><<<GRID(768), blk, 0, stream>>>(hidden, CHID, Wb2at, 1536, y2, 768);
    // ---- 8. final residual ----
    gateadd_k<<<e768, blk, 0, stream>>>(H_anew, G_gates, 768, op_b, y2, out);
#undef GRID

    (void)in_sizes; (void)n_in; (void)out_size; (void)ws_size;
}

// Round 11
// 561.532 us; speedup vs baseline: 1.2837x; 1.2837x over previous
//
#include <hip/hip_runtime.h>
#include <math.h>

// Problem constants
constexpr int CB = 2, CN = 1024, CD = 768, CH = 16, CHD = 48, CHID = 1536;
constexpr int CT = CB * CN;              // 2048 tokens
constexpr float CEPS = 1e-5f;

typedef __bf16 bf16_t;
typedef __bf16 bf16x8 __attribute__((ext_vector_type(8)));
typedef __bf16 bf16x4 __attribute__((ext_vector_type(4)));
typedef float  f32x4  __attribute__((ext_vector_type(4)));

__device__ __forceinline__ float sigf(float x) { return 1.f / (1.f + expf(-x)); }

// async global->LDS, 16B per lane, LDS dest = wave-uniform base + lane*16
__device__ __forceinline__ void gload16(const void* g, void* l) {
    __builtin_amdgcn_global_load_lds((const __attribute__((address_space(1))) void*)g,
                                     (__attribute__((address_space(3))) void*)l, 16, 0, 0);
}

// ---------------------------------------------------------------------------
// LN-pre: an = LN(a) (fp32), snbf = bf16(LN(s)*snw), optional sbf = bf16(s).
// One 256-thread block per token row.
// ---------------------------------------------------------------------------
__global__ __launch_bounds__(256) void ln_pre_k(
    const float* __restrict__ a, const float* __restrict__ s,
    const float* __restrict__ snw,
    float* __restrict__ an, bf16_t* __restrict__ snbf, bf16_t* __restrict__ sbf)
{
    __shared__ float r4[4][4];
    const int row = blockIdx.x;
    const int tid = threadIdx.x;
    const float* ar = a + (size_t)row * CD;
    const float* sr = s + (size_t)row * CD;

    float av[3], sv[3];
    float suma = 0.f, sqa = 0.f, sums = 0.f, sqs = 0.f;
#pragma unroll
    for (int j = 0; j < 3; ++j) {
        const int i = tid + j * 256;
        av[j] = ar[i]; sv[j] = sr[i];
        suma += av[j]; sqa += av[j] * av[j];
        sums += sv[j]; sqs += sv[j] * sv[j];
    }
#pragma unroll
    for (int o = 32; o > 0; o >>= 1) {
        suma += __shfl_down(suma, o, 64);
        sqa  += __shfl_down(sqa,  o, 64);
        sums += __shfl_down(sums, o, 64);
        sqs  += __shfl_down(sqs,  o, 64);
    }
    const int wv = tid >> 6;
    if ((tid & 63) == 0) { r4[0][wv] = suma; r4[1][wv] = sqa; r4[2][wv] = sums; r4[3][wv] = sqs; }
    __syncthreads();
    suma = r4[0][0] + r4[0][1] + r4[0][2] + r4[0][3];
    sqa  = r4[1][0] + r4[1][1] + r4[1][2] + r4[1][3];
    sums = r4[2][0] + r4[2][1] + r4[2][2] + r4[2][3];
    sqs  = r4[3][0] + r4[3][1] + r4[3][2] + r4[3][3];

    const float inv_d = 1.f / (float)CD;
    const float ma = suma * inv_d;
    const float ra = rsqrtf(sqa * inv_d - ma * ma + CEPS);
    const float ms = sums * inv_d;
    const float rs = rsqrtf(sqs * inv_d - ms * ms + CEPS);

#pragma unroll
    for (int j = 0; j < 3; ++j) {
        const int i = tid + j * 256;
        an[(size_t)row * CD + i]   = (av[j] - ma) * ra;
        snbf[(size_t)row * CD + i] = (bf16_t)((sv[j] - ms) * rs * snw[i]);
        if (sbf) sbf[(size_t)row * CD + i] = (bf16_t)sv[j];
    }
}

// ---------------------------------------------------------------------------
// Merged transpose-convert: all 15 weight packs in ONE dispatch.
// Each 32x32 tile: dst[row_ofs+n][k] = bf16(src[k][col_ofs+n]).
// ---------------------------------------------------------------------------
struct TJob { const float* src; bf16_t* dst; int ld_src, col_ofs, ld_dst, row_ofs, ntx, cnt; };
struct TJobs { TJob j[15]; };

__global__ __launch_bounds__(256) void tcvt_all_k(TJobs jobs)
{
    __shared__ float t[32][33];
    int tb = blockIdx.x;
    int ji = 0;
    while (ji < 14 && tb >= jobs.j[ji].cnt) { tb -= jobs.j[ji].cnt; ++ji; }
    const float* src = jobs.j[ji].src;
    bf16_t* dst      = jobs.j[ji].dst;
    const int ld_src = jobs.j[ji].ld_src, col_ofs = jobs.j[ji].col_ofs;
    const int ld_dst = jobs.j[ji].ld_dst, row_ofs = jobs.j[ji].row_ofs;
    const int ntx    = jobs.j[ji].ntx;
    const int n0 = (tb % ntx) * 32;
    const int k0 = (tb / ntx) * 32;
    const int tx = threadIdx.x & 31, ty = threadIdx.x >> 5;   // ty 0..7
#pragma unroll
    for (int i = 0; i < 4; ++i)
        t[ty + 8 * i][tx] = src[(size_t)(k0 + ty + 8 * i) * ld_src + col_ofs + n0 + tx];
    __syncthreads();
#pragma unroll
    for (int i = 0; i < 4; ++i)
        dst[(size_t)(row_ofs + n0 + ty + 8 * i) * ld_dst + k0 + tx] = (bf16_t)t[tx][ty + 8 * i];
}

// ---------------------------------------------------------------------------
// bf16 MFMA GEMM: C[M,N] = A[M,K] @ B[K,N], with B stored TRANSPOSED: Bt[N][K].
// 128x128 tile, BK=32, 256 threads = 4 waves (2x2), each wave 64x64 out
// (4x4 fragments of 16x16, mfma_f32_16x16x32_bf16). Double-buffered LDS
// staged via global_load_lds (m97 structure). fp32 accumulate; C fp32 or bf16.
// ---------------------------------------------------------------------------
template<bool CBF16>
__global__ __launch_bounds__(256) void mgemm_k(
    const bf16_t* __restrict__ A, const int lda,
    const bf16_t* __restrict__ Bt, const int K,
    void* __restrict__ Cv, const int ldc)
{
    __shared__ __align__(16) bf16_t lA[2][128 * 32];
    __shared__ __align__(16) bf16_t lB[2][128 * 32];
    const int tid  = threadIdx.x;
    const int lane = tid & 63;
    const int m0 = blockIdx.y * 128;
    const int n0 = blockIdx.x * 128;
    const int wv = tid >> 6;
    const int wr = (wv >> 1) * 64;
    const int wc = (wv & 1) * 64;

    f32x4 acc[4][4] = {};

    // staging geometry: chunk c (16B) -> row c>>2, k-group c&3 (8 bf16)
    const int r0 = tid >> 2,        kg0 = (tid & 3) * 8;          // issue 0 chunk=tid
    const int r1 = (tid + 256) >> 2, kg1 = kg0;                   // issue 1 chunk=tid+256
    const int wbase = (tid & ~63) * 16;                           // wave-uniform LDS byte base

#define STAGE(buf, kt)                                                                  \
    do {                                                                                \
        gload16(A  + (size_t)(m0 + r0) * lda + (kt) + kg0, (char*)lA[buf] + wbase);     \
        gload16(A  + (size_t)(m0 + r1) * lda + (kt) + kg1, (char*)lA[buf] + 4096 + wbase); \
        gload16(Bt + (size_t)(n0 + r0) * K   + (kt) + kg0, (char*)lB[buf] + wbase);     \
        gload16(Bt + (size_t)(n0 + r1) * K   + (kt) + kg1, (char*)lB[buf] + 4096 + wbase); \
    } while (0)

    const int nt = K >> 5;
    STAGE(0, 0);
    __syncthreads();

    const int afr = wr + (lane & 15);
    const int bfr_ = wc + (lane & 15);
    const int kof = (lane >> 4) * 8;

    for (int t = 0; t < nt; ++t) {
        const int buf = t & 1;
        if (t + 1 < nt) STAGE(buf ^ 1, (t + 1) << 5);
        bf16x8 af[4], bfv[4];
#pragma unroll
        for (int i = 0; i < 4; ++i) {
            af[i]  = *(const bf16x8*)&lA[buf][(afr + i * 16) * 32 + kof];
            bfv[i] = *(const bf16x8*)&lB[buf][(bfr_ + i * 16) * 32 + kof];
        }
#pragma unroll
        for (int mi = 0; mi < 4; ++mi)
#pragma unroll
            for (int ni = 0; ni < 4; ++ni)
                acc[mi][ni] = __builtin_amdgcn_mfma_f32_16x16x32_bf16(af[mi], bfv[ni], acc[mi][ni], 0, 0, 0);
        __syncthreads();
    }
#undef STAGE

    // C/D layout: col = lane&15, row = (lane>>4)*4 + reg   [verified m89/m91]
    const int crow = m0 + wr + ((lane >> 4) << 2);
    const int ccol = n0 + wc + (lane & 15);
#pragma unroll
    for (int mi = 0; mi < 4; ++mi)
#pragma unroll
        for (int r = 0; r < 4; ++r) {
            const size_t ro = (size_t)(crow + mi * 16 + r) * ldc + ccol;
#pragma unroll
            for (int ni = 0; ni < 4; ++ni) {
                if (CBF16) ((bf16_t*)Cv)[ro + ni * 16] = (bf16_t)acc[mi][ni][r];
                else       ((float*)Cv)[ro + ni * 16]  = acc[mi][ni][r];
            }
        }
}

// ---------------------------------------------------------------------------
// Elementwise combines (all fp32 math, 4 elements/thread, exact grids)
// ---------------------------------------------------------------------------
// b = an * sigmoid(ss + ssb) + sb ; ss|sb packed [T][1536] bf16
__global__ __launch_bounds__(256) void comb_adaln_k(
    const float* __restrict__ an, const bf16_t* __restrict__ ssb_mat,
    const float* __restrict__ bias, bf16_t* __restrict__ out)
{
    const int i4 = (blockIdx.x * 256 + threadIdx.x) * 4;
    const int row = i4 / CD, col = i4 - row * CD;
    const float4 anv = *(const float4*)&an[i4];
    const bf16x4 ssv = *(const bf16x4*)&ssb_mat[(size_t)row * 1536 + col];
    const bf16x4 sbv = *(const bf16x4*)&ssb_mat[(size_t)row * 1536 + 768 + col];
    const float4 bv  = *(const float4*)&bias[col];
    bf16x4 o;
    o[0] = (bf16_t)(anv.x * sigf((float)ssv[0] + bv.x) + (float)sbv[0]);
    o[1] = (bf16_t)(anv.y * sigf((float)ssv[1] + bv.y) + (float)sbv[1]);
    o[2] = (bf16_t)(anv.z * sigf((float)ssv[2] + bv.z) + (float)sbv[2]);
    o[3] = (bf16_t)(anv.w * sigf((float)ssv[3] + bv.w) + (float)sbv[3]);
    *(bf16x4*)&out[i4] = o;
}

// dst = base + sigmoid(gate_pre + bias) * x   (gates [T][1536] fp32, col offset g_ofs)
__global__ __launch_bounds__(256) void gateadd_k(
    const float* __restrict__ base, const float* __restrict__ gates, const int g_ofs,
    const float* __restrict__ bias, const float* __restrict__ x, float* __restrict__ dst)
{
    const int i4 = (blockIdx.x * 256 + threadIdx.x) * 4;
    const int row = i4 / CD, col = i4 - row * CD;
    const float4 bv = *(const float4*)&base[i4];
    const float4 gv = *(const float4*)&gates[(size_t)row * 1536 + g_ofs + col];
    const float4 bi = *(const float4*)&bias[col];
    const float4 xv = *(const float4*)&x[i4];
    float4 o;
    o.x = bv.x + sigf(gv.x + bi.x) * xv.x;
    o.y = bv.y + sigf(gv.y + bi.y) * xv.y;
    o.z = bv.z + sigf(gv.z + bi.z) * xv.z;
    o.w = bv.w + sigf(gv.w + bi.w) * xv.w;
    *(float4*)&dst[i4] = o;
}

// hidden = silu(gate) * u * h ; ugh packed [T][4608] bf16 (u|gate|h)
__global__ __launch_bounds__(256) void mlp_comb_k(
    const bf16_t* __restrict__ ugh, bf16_t* __restrict__ hidden)
{
    const int i4 = (blockIdx.x * 256 + threadIdx.x) * 4;
    const int row = i4 / CHID, col = i4 - row * CHID;
    const bf16x4 uv = *(const bf16x4*)&ugh[(size_t)row * 4608 + col];
    const bf16x4 gv = *(const bf16x4*)&ugh[(size_t)row * 4608 + 1536 + col];
    const bf16x4 hv = *(const bf16x4*)&ugh[(size_t)row * 4608 + 3072 + col];
    bf16x4 o;
#pragma unroll
    for (int j = 0; j < 4; ++j) {
        const float g = (float)gv[j];
        o[j] = (bf16_t)(g * sigf(g) * (float)uv[j] * (float)hv[j]);
    }
    *(bf16x4*)&hidden[i4] = o;
}

// ---------------------------------------------------------------------------
// Flash attention, fp32 (round-7 proven version: 64 q-rows/block, 4
// threads/row, 16 keys/thread — measured 171.5 us, LDS-BW-bound).
// q/k/v strided out of fused qkvg [T][3072]; fuses q-bias on load and
// og = o * sigmoid(g) epilogue (bf16 out). Keys interleaved key = kk*4+quad
// so quad-group LDS reads hit disjoint banks (row stride 52 words).
// ---------------------------------------------------------------------------
__global__ __launch_bounds__(256) void attn_k(
    const float* __restrict__ qkvg, const float* __restrict__ qb,
    const float* __restrict__ z, bf16_t* __restrict__ og)
{
    __shared__ float kls[64][52];
    __shared__ float vls[64][52];
    const int tid  = threadIdx.x;
    const int qb_i = blockIdx.x;
    const int h    = blockIdx.y;
    const int b    = blockIdx.z;
    const int r    = tid >> 2;
    const int quad = tid & 3;
    const int qrow = qb_i * 64 + r;
    const float scale = 0.14433756729740643f; // 1/sqrt(48)

    float qreg[48];
    const float* qp = qkvg + (size_t)(b * CN + qrow) * 3072 + h * CHD;
#pragma unroll
    for (int j = 0; j < 12; ++j) {
        const float4 t4 = *(const float4*)(qp + j * 4);
        const float4 b4 = *(const float4*)(qb + h * CHD + j * 4);
        qreg[j * 4 + 0] = t4.x + b4.x; qreg[j * 4 + 1] = t4.y + b4.y;
        qreg[j * 4 + 2] = t4.z + b4.z; qreg[j * 4 + 3] = t4.w + b4.w;
    }
    float acc[48];
#pragma unroll
    for (int d = 0; d < 48; ++d) acc[d] = 0.f;
    float m = -1e30f, l = 0.f;

    const float* zbase = z + (((size_t)(h * CB + b)) * CN + qrow) * CN;
    const float* kbase = qkvg + 768  + h * CHD;
    const float* vbase = qkvg + 1536 + h * CHD;

    for (int kt = 0; kt < CN; kt += 64) {
        __syncthreads();
#pragma unroll
        for (int j = 0; j < 3; ++j) {
            const int idx = tid + j * 256;       // 0..767
            const int key = idx / 12;
            const int d4  = idx - key * 12;
            const size_t gofs = (size_t)(b * CN + kt + key) * 3072 + d4 * 4;
            *(float4*)&kls[key][d4 * 4] = *(const float4*)(kbase + gofs);
            *(float4*)&vls[key][d4 * 4] = *(const float4*)(vbase + gofs);
        }
        __syncthreads();

        float sc[16];
#pragma unroll
        for (int kk = 0; kk < 16; ++kk) {
            const int key = kk * 4 + quad;
            float dt = 0.f;
#pragma unroll
            for (int j = 0; j < 12; ++j) {
                const float4 k4 = *(const float4*)&kls[key][j * 4];
                dt = fmaf(qreg[j * 4 + 0], k4.x, dt);
                dt = fmaf(qreg[j * 4 + 1], k4.y, dt);
                dt = fmaf(qreg[j * 4 + 2], k4.z, dt);
                dt = fmaf(qreg[j * 4 + 3], k4.w, dt);
            }
            sc[kk] = dt * scale + zbase[kt + key];
        }
        float tmax = sc[0];
#pragma unroll
        for (int kk = 1; kk < 16; ++kk) tmax = fmaxf(tmax, sc[kk]);
        tmax = fmaxf(tmax, __shfl_xor(tmax, 1, 4));
        tmax = fmaxf(tmax, __shfl_xor(tmax, 2, 4));
        const float mnew = fmaxf(m, tmax);
        const float resc = expf(m - mnew);
        m = mnew;
        l *= resc;
#pragma unroll
        for (int d = 0; d < 48; ++d) acc[d] *= resc;

        float p[16]; float ps = 0.f;
#pragma unroll
        for (int kk = 0; kk < 16; ++kk) { p[kk] = expf(sc[kk] - mnew); ps += p[kk]; }
        l += ps;

#pragma unroll
        for (int kk = 0; kk < 16; ++kk) {
            const int key = kk * 4 + quad;
            const float pv = p[kk];
#pragma unroll
            for (int j = 0; j < 12; ++j) {
                const float4 v4 = *(const float4*)&vls[key][j * 4];
                acc[j * 4 + 0] = fmaf(pv, v4.x, acc[j * 4 + 0]);
                acc[j * 4 + 1] = fmaf(pv, v4.y, acc[j * 4 + 1]);
                acc[j * 4 + 2] = fmaf(pv, v4.z, acc[j * 4 + 2]);
                acc[j * 4 + 3] = fmaf(pv, v4.w, acc[j * 4 + 3]);
            }
        }
    }

    // reduce partials across the 4-thread quad group
    l += __shfl_xor(l, 1, 4);
    l += __shfl_xor(l, 2, 4);
    const float inv = 1.f / l;
#pragma unroll
    for (int d = 0; d < 48; ++d) {
        acc[d] += __shfl_xor(acc[d], 1, 4);
        acc[d] += __shfl_xor(acc[d], 2, 4);
    }
    if (quad == 0) {
        const float* gp = qkvg + (size_t)(b * CN + qrow) * 3072 + 2304 + h * CHD;
        bf16_t* op = og + (size_t)(b * CN + qrow) * CD + h * CHD;
#pragma unroll
        for (int j = 0; j < 12; ++j) {
            const float4 gv = *(const float4*)(gp + j * 4);
            bf16x4 o;
            o[0] = (bf16_t)(acc[j * 4 + 0] * inv * sigf(gv.x));
            o[1] = (bf16_t)(acc[j * 4 + 1] * inv * sigf(gv.y));
            o[2] = (bf16_t)(acc[j * 4 + 2] * inv * sigf(gv.z));
            o[3] = (bf16_t)(acc[j * 4 + 3] * inv * sigf(gv.w));
            *(bf16x4*)(op + j * 4) = o;
        }
    }
}

// ---------------------------------------------------------------------------
// launch
// ---------------------------------------------------------------------------
extern "C" void kernel_launch(void* const* d_in, const int* in_sizes, int n_in,
                              void* d_out, int out_size, void* d_ws, size_t ws_size,
                              hipStream_t stream)
{
    const float* a       = (const float*)d_in[0];
    const float* s       = (const float*)d_in[1];
    const float* z       = (const float*)d_in[2];
    const float* a1_snw  = (const float*)d_in[3];
    const float* a1_ssw  = (const float*)d_in[4];
    const float* a1_ssb  = (const float*)d_in[5];
    const float* a1_sbw  = (const float*)d_in[6];
    const float* q_w     = (const float*)d_in[7];
    const float* q_b     = (const float*)d_in[8];
    const float* k_w     = (const float*)d_in[9];
    const float* v_w     = (const float*)d_in[10];
    const float* g_w     = (const float*)d_in[11];
    const float* o_w     = (const float*)d_in[12];
    const float* outproj_w = (const float*)d_in[13];
    const float* outproj_b = (const float*)d_in[14];
    const float* a2_snw  = (const float*)d_in[15];
    const float* a2_ssw  = (const float*)d_in[16];
    const float* a2_ssb  = (const float*)d_in[17];
    const float* a2_sbw  = (const float*)d_in[18];
    const float* swish_w = (const float*)d_in[19];
    const float* a2b_w   = (const float*)d_in[20];
    const float* b2a_w   = (const float*)d_in[21];
    const float* op_w    = (const float*)d_in[22];
    const float* op_b    = (const float*)d_in[23];
    float* out = (float*)d_out;
    char*  wsb = (char*)d_ws;

    // ---- workspace slabs (aligned 256B); ~95 MB total ----
    size_t off = 0;
    auto alloc = [&](size_t bytes) { char* p = wsb + off; off = (off + bytes + 255) & ~(size_t)255; return p; };
    float*  A_an    = (float*) alloc((size_t)CT * CD * 4);     // an / an2 / y2
    bf16_t* B_sn    = (bf16_t*)alloc((size_t)CT * CD * 2);     // sn / sn2
    bf16_t* C_sbf   = (bf16_t*)alloc((size_t)CT * CD * 2);     // bf16(s)
    bf16_t* D_ssb   = (bf16_t*)alloc((size_t)CT * 1536 * 2);   // ss|sb (x2) / hidden
    bf16_t* E_act   = (bf16_t*)alloc((size_t)CT * CD * 2);     // b_bf / og_bf / a2_bf
    char*   F_big   = (char*)  alloc((size_t)CT * 3072 * 4);   // qkvg f32 / ugh bf16
    float*  G_gates = (float*) alloc((size_t)CT * 1536 * 4);   // gate pre-acts (live to end)
    float*  H_anew  = (float*) alloc((size_t)CT * CD * 4);
    float*  J_x     = (float*) alloc((size_t)CT * CD * 4);
    bf16_t* W1t     = (bf16_t*)alloc((size_t)1536 * 768 * 2);  // [ssw|sbw]^T
    bf16_t* W2t     = (bf16_t*)alloc((size_t)1536 * 768 * 2);
    bf16_t* Wqkvgt  = (bf16_t*)alloc((size_t)3072 * 768 * 2);
    bf16_t* Wgt     = (bf16_t*)alloc((size_t)1536 * 768 * 2);  // [outproj|op]^T
    bf16_t* W3t     = (bf16_t*)alloc((size_t)4608 * 768 * 2);  // [u|gate|a2b]^T
    bf16_t* Wot     = (bf16_t*)alloc((size_t)768 * 768 * 2);
    bf16_t* Wb2at   = (bf16_t*)alloc((size_t)768 * 1536 * 2);
    float*  qkvg_f  = (float*)F_big;
    bf16_t* ugh_b   = (bf16_t*)F_big;
    bf16_t* hidden  = D_ssb;
    float*  y2      = A_an;

    const dim3 blk(256);

    // ---- 1. pack weights -> transposed bf16 (single dispatch, 10944 tiles) ----
    TJobs tj = {{
        {a1_ssw,    W1t,    768,  0,    768,  0,    24, 576},
        {a1_sbw,    W1t,    768,  0,    768,  768,  24, 576},
        {q_w,       Wqkvgt, 768,  0,    768,  0,    24, 576},
        {k_w,       Wqkvgt, 768,  0,    768,  768,  24, 576},
        {v_w,       Wqkvgt, 768,  0,    768,  1536, 24, 576},
        {g_w,       Wqkvgt, 768,  0,    768,  2304, 24, 576},
        {outproj_w, Wgt,    768,  0,    768,  0,    24, 576},
        {op_w,      Wgt,    768,  0,    768,  768,  24, 576},
        {a2_ssw,    W2t,    768,  0,    768,  0,    24, 576},
        {a2_sbw,    W2t,    768,  0,    768,  768,  24, 576},
        {swish_w,   W3t,    3072, 0,    768,  0,    48, 1152},
        {swish_w,   W3t,    3072, 1536, 768,  1536, 48, 1152},
        {a2b_w,     W3t,    1536, 0,    768,  3072, 48, 1152},
        {o_w,       Wot,    768,  0,    768,  0,    24, 576},
        {b2a_w,     Wb2at,  768,  0,    1536, 0,    24, 1152},
    }};
    tcvt_all_k<<<dim3(10944), blk, 0, stream>>>(tj);

    const dim3 e768(CT * CD / 4 / 256);       // 1536 blocks
    const dim3 e1536(CT * CHID / 4 / 256);    // 3072 blocks
#define GRID(N) dim3((N) / 128, CT / 128)

    // ---- 2. adaln1 ----
    ln_pre_k<<<CT, blk, 0, stream>>>(a, s, a1_snw, A_an, B_sn, C_sbf);
    mgemm_k<true ><<<GRID(1536), blk, 0, stream>>>(B_sn, CD, W1t, 768, D_ssb, 1536);
    comb_adaln_k<<<e768, blk, 0, stream>>>(A_an, D_ssb, a1_ssb, E_act);
    // ---- 3. qkvg + gates ----
    mgemm_k<false><<<GRID(3072), blk, 0, stream>>>(E_act, CD, Wqkvgt, 768, qkvg_f, 3072);
    mgemm_k<false><<<GRID(1536), blk, 0, stream>>>(C_sbf, CD, Wgt, 768, G_gates, 1536);
    // ---- 4. attention (writes og = o*sigmoid(g), bf16) ----
    attn_k<<<dim3(CN / 64, CH, CB), blk, 0, stream>>>(qkvg_f, q_b, z, E_act);
    // ---- 5. x = og @ o_w ; anew = a + sigmoid(outproj)*x ----
    mgemm_k<false><<<GRID(768), blk, 0, stream>>>(E_act, CD, Wot, 768, J_x, 768);
    gateadd_k<<<e768, blk, 0, stream>>>(a, G_gates, 0, outproj_b, J_x, H_anew);
    // ---- 6. adaln2 ----
    ln_pre_k<<<CT, blk, 0, stream>>>(H_anew, s, a2_snw, A_an, B_sn, nullptr);
    mgemm_k<true ><<<GRID(1536), blk, 0, stream>>>(B_sn, CD, W2t, 768, D_ssb, 1536);
    comb_adaln_k<<<e768, blk, 0, stream>>>(A_an, D_ssb, a2_ssb, E_act);
    // ---- 7. MLP ----
    mgemm_k<true ><<<GRID(4608), blk, 0, stream>>>(E_act, CD, W3t, 768, ugh_b, 4608);
    mlp_comb_k<<<e1536, blk, 0, stream>>>(ugh_b, hidden);
    mgemm_k<false><<<GRID(768), blk, 0, stream>>>(hidden, CHID, Wb2at, 1536, y2, 768);
    // ---- 8. final residual ----
    gateadd_k<<<e768, blk, 0, stream>>>(H_anew, G_gates, 768, op_b, y2, out);
#undef GRID

    (void)in_sizes; (void)n_in; (void)out_size; (void)ws_size;
}